// Round 2
// 7535.134 us; speedup vs baseline: 1.2777x; 1.2777x over previous
//
#include <hip/hip_runtime.h>
#include <stdint.h>

#define TT 2048
#define BB 8
#define II 512
#define HH 512
#define GG 32           // workgroups per direction
#define HS 16           // hidden units per WG
#define SLOT (BB*HH)    // 4096 bf16 elems per h-history slot

typedef __attribute__((ext_vector_type(8))) short short8;
typedef __attribute__((ext_vector_type(4))) float float4v;

__device__ __forceinline__ unsigned short f2bf(float f) {
  unsigned u = __builtin_bit_cast(unsigned, f);
  u = u + 0x7FFFu + ((u >> 16) & 1u);   // RNE
  return (unsigned short)(u >> 16);
}

__device__ __forceinline__ float fsigmoid(float x) {
  return __fdividef(1.0f, 1.0f + __expf(-x));
}
__device__ __forceinline__ float ftanh(float x) {
  float e = __expf(-2.0f * fabsf(x));   // in (0,1], never overflows
  float r = __fdividef(1.0f - e, 1.0f + e);
  return x < 0.0f ? -r : r;
}

// input[b][t][k] fp32  ->  xbf[t][b][k] bf16
__global__ void xprep_kernel(const float* __restrict__ x,
                             unsigned short* __restrict__ xbf) {
  int idx = blockIdx.x * 256 + threadIdx.x;   // 1,048,576 threads, 8 elems each
  int k8 = idx & 63;
  int bt = idx >> 6;
  int t  = bt & (TT - 1);
  int b  = bt >> 11;
  const float* src = x + ((size_t)b * TT + t) * II + (size_t)k8 * 8;
  float4v v0 = *(const float4v*)src;
  float4v v1 = *(const float4v*)(src + 4);
  short8 o;
  o[0] = (short)f2bf(v0[0]); o[1] = (short)f2bf(v0[1]);
  o[2] = (short)f2bf(v0[2]); o[3] = (short)f2bf(v0[3]);
  o[4] = (short)f2bf(v1[0]); o[5] = (short)f2bf(v1[1]);
  o[6] = (short)f2bf(v1[2]); o[7] = (short)f2bf(v1[3]);
  *(short8*)(xbf + ((size_t)t * BB + b) * II + (size_t)k8 * 8) = o;
}

// XCD-pinned persistent LSTM: dir0 lives entirely on XCD0, dir1 on XCD1.
// All h/flag exchange stays inside one per-XCD L2 (CDNA vector L1 is
// write-through, so stores land in L2; sc0 loads bypass L1) instead of the
// MALL round trip that agent scope forces.
__global__ __launch_bounds__(256, 1) void lstm_kernel(
    const float* __restrict__ Wih_f, const float* __restrict__ Whh_f,
    const float* __restrict__ bih_f, const float* __restrict__ bhh_f,
    const float* __restrict__ Wih_b, const float* __restrict__ Whh_b,
    const float* __restrict__ bih_b, const float* __restrict__ bhh_b,
    const unsigned short* __restrict__ xbf,
    unsigned short* __restrict__ h_hist,
    int* __restrict__ flags,
    int* __restrict__ claim,
    float* __restrict__ out)
{
  __shared__ int s_role;
  __shared__ float lds_g[4][16][17];   // [gate][row][batch], +1 pad

  const int tid  = threadIdx.x;

  // ---- role claim: bind (dir, slice) to the XCD we actually landed on ----
  if (tid == 0) {
    int xcc;
    asm volatile("s_getreg_b32 %0, hwreg(HW_REG_XCC_ID)" : "=s"(xcc));
    int role = -1;
    if (xcc < 2) {
      int r = atomicAdd(&claim[xcc], 1);      // device-scope, startup-only
      if (r < GG) role = xcc * GG + r;
    }
    s_role = role;
  }
  __syncthreads();
  const int role = s_role;
  if (role < 0) return;                        // surplus WG: exit immediately
  const int dir = role >> 5;
  const int wg  = role & 31;

  const int wave = tid >> 6;          // gate type: 0=i 1=f 2=g 3=o
  const int lane = tid & 63;
  const int m    = lane & 15;         // A-row within tile / B-col (batch)
  const int q    = lane >> 4;         // quad
  const bool nv  = (m < BB);          // batch lane valid

  const float* __restrict__ Wih = dir ? Wih_b : Wih_f;
  const float* __restrict__ Whh = dir ? Whh_b : Whh_f;
  const float* __restrict__ bih = dir ? bih_b : bih_f;
  const float* __restrict__ bhh = dir ? bhh_b : bhh_f;

  const int j0   = wg * HS;                 // hidden slice [j0, j0+16)
  const int grow = wave * HH + j0 + m;      // gate row this lane loads (A[m][k])

  // ---- persistent weight A-fragments (A[m=lane&15][k=q*8+j]) ----
  short8 a_x[16], a_h[16];
#pragma unroll
  for (int kf = 0; kf < 16; ++kf) {
    const float* p1 = Wih + (size_t)grow * II + kf * 32 + q * 8;
    const float* p2 = Whh + (size_t)grow * HH + kf * 32 + q * 8;
    short8 A, Bv;
#pragma unroll
    for (int j = 0; j < 8; ++j) {
      A[j]  = (short)f2bf(p1[j]);
      Bv[j] = (short)f2bf(p2[j]);
    }
    a_x[kf] = A;
    a_h[kf] = Bv;
  }

  // ---- epilogue-persistent state (threads 0..127: one (jj, bb) cell each) ----
  float c_state = 0.0f;
  float bias_i = 0.f, bias_ff = 0.f, bias_g = 0.f, bias_o = 0.f;
  const int jj = tid & 15;
  const int bb = tid >> 4;
  if (tid < 128) {
    int j = j0 + jj;
    bias_i  = bih[0 * HH + j] + bhh[0 * HH + j];
    bias_ff = bih[1 * HH + j] + bhh[1 * HH + j];
    bias_g  = bih[2 * HH + j] + bhh[2 * HH + j];
    bias_o  = bih[3 * HH + j] + bhh[3 * HH + j];
  }

  unsigned short* __restrict__ hh = h_hist + (size_t)dir * (TT + 1) * SLOT;
  int* __restrict__ flg = flags + dir * TT * GG;
  int bailleft = 2000000;   // safety: never hang the harness

#pragma unroll 1
  for (int s = 0; s < TT; ++s) {
    const int t = dir ? (TT - 1 - s) : s;

    float4v acc[4];
#pragma unroll
    for (int i = 0; i < 4; ++i) acc[i] = (float4v){0.f, 0.f, 0.f, 0.f};

    // ---- x contribution: independent of recurrence, overlaps the wait ----
    {
      const unsigned short* xrow =
          xbf + ((size_t)t * BB + (nv ? m : 0)) * II + q * 8;
      short8 bx[16];
#pragma unroll
      for (int kf = 0; kf < 16; ++kf) {
        short8 v = {0, 0, 0, 0, 0, 0, 0, 0};
        if (nv) v = *(const short8*)(xrow + kf * 32);
        bx[kf] = v;
      }
#pragma unroll
      for (int kf = 0; kf < 16; ++kf)
        acc[kf & 3] = __builtin_amdgcn_mfma_f32_16x16x32_bf16(
            a_x[kf], bx[kf], acc[kf & 3], 0, 0, 0);
    }

    // ---- wait for h(s-1) flags from all 32 WGs of this direction ----
    // wave 0 polls (L2-scope sc0 loads); waves 1..3 park at the barrier so
    // the contended flag line sees 1/4 the poll traffic.
    if (s > 0) {
      if (wave == 0) {
        const int* fl = flg + (size_t)(s - 1) * GG + (lane & 31);
        for (;;) {
          int v;
          asm volatile("global_load_dword %0, %1, off sc0\n\t"
                       "s_waitcnt vmcnt(0)"
                       : "=v"(v) : "v"(fl) : "memory");
          if (__ballot(v == 0) == 0ull) break;
          if (--bailleft < 0) break;
        }
      }
      __syncthreads();
    }

    // ---- h contribution (sc0 loads: bypass L1, served by this XCD's L2) ----
    {
      const unsigned short* hrow =
          hh + (size_t)s * SLOT + (size_t)(nv ? m : 0) * HH + q * 8;
      short8 bh[16];
#pragma unroll
      for (int kf = 0; kf < 16; ++kf)
        asm volatile("global_load_dwordx4 %0, %1, off sc0"
                     : "=&v"(bh[kf]) : "v"(hrow + kf * 32) : "memory");
      asm volatile("s_waitcnt vmcnt(0)" ::: "memory");
      __builtin_amdgcn_sched_barrier(0);   // rule #18: keep MFMAs below the wait
      // lanes m>=8 hold row-0 data; their output columns are never read.
#pragma unroll
      for (int kf = 0; kf < 16; ++kf)
        acc[kf & 3] = __builtin_amdgcn_mfma_f32_16x16x32_bf16(
            a_h[kf], bh[kf], acc[kf & 3], 0, 0, 0);
    }

    // ---- gates to LDS (C/D layout: col=lane&15, row=q*4+r) ----
#pragma unroll
    for (int r = 0; r < 4; ++r) {
      float g = acc[0][r] + acc[1][r] + acc[2][r] + acc[3][r];
      lds_g[wave][q * 4 + r][m] = g;
    }
    __syncthreads();

    // ---- elementwise LSTM cell update; c persistent in registers ----
    if (tid < 128) {
      float gi = lds_g[0][jj][bb] + bias_i;
      float gf = lds_g[1][jj][bb] + bias_ff;
      float gg = lds_g[2][jj][bb] + bias_g;
      float go = lds_g[3][jj][bb] + bias_o;
      float si = fsigmoid(gi);
      float sf = fsigmoid(gf);
      float tg = ftanh(gg);
      float so = fsigmoid(go);
      c_state = sf * c_state + si * tg;
      float hv = so * ftanh(c_state);
      // publish h into this XCD's L2 (L1 is write-through; sc0 for symmetry)
      unsigned short* hp =
          hh + (size_t)(s + 1) * SLOT + (size_t)bb * HH + j0 + jj;
      unsigned int hb = f2bf(hv);
      asm volatile("global_store_short %0, %1, off sc0"
                   :: "v"(hp), "v"(hb) : "memory");
      __builtin_nontemporal_store(
          hv, &out[((size_t)t * BB + bb) * (2 * HH) + (size_t)dir * HH + j0 + jj]);
    }
    // drain our stores (asm stores are invisible to the compiler's barrier
    // lowering), then barrier: all waves' h stores are in L2 before release.
    asm volatile("s_waitcnt vmcnt(0)" ::: "memory");
    __syncthreads();

    if (tid == 0) {
      int* fp = flg + (size_t)s * GG + wg;
      int one = 1;
      asm volatile("global_store_dword %0, %1, off sc0"
                   :: "v"(fp), "v"(one) : "memory");
    }
  }
}

extern "C" void kernel_launch(void* const* d_in, const int* in_sizes, int n_in,
                              void* d_out, int out_size, void* d_ws, size_t ws_size,
                              hipStream_t stream) {
  (void)in_sizes; (void)n_in; (void)out_size; (void)ws_size;
  const float* input = (const float*)d_in[0];
  const float* Wih_f = (const float*)d_in[1];
  const float* Whh_f = (const float*)d_in[2];
  const float* bih_f = (const float*)d_in[3];
  const float* bhh_f = (const float*)d_in[4];
  const float* Wih_b = (const float*)d_in[5];
  const float* Whh_b = (const float*)d_in[6];
  const float* bih_b = (const float*)d_in[7];
  const float* bhh_b = (const float*)d_in[8];

  char* ws = (char*)d_ws;
  // layout (total 50,872,320 B — identical to the proven footprint):
  //   [xbf 16,777,216 B][h_hist used 33,562,624 B | spare 8,192 B][flags 524,288 B]
  // claim (32 B) lives in the h_hist spare tail — NO growth past flags end.
  unsigned short* xbf    = (unsigned short*)(ws);
  unsigned short* h_hist = (unsigned short*)(ws + 16777216);
  int*            claim  = (int*)(ws + 50339840);   // 16777216 + 33562624
  int*            flags  = (int*)(ws + 50348032);

  hipMemsetAsync(flags, 0, 2 * TT * GG * sizeof(int), stream);
  hipMemsetAsync(claim, 0, 32, stream);
  hipMemsetAsync(h_hist, 0, SLOT * 2, stream);                                // dir0 h(-1)=0
  hipMemsetAsync((char*)h_hist + (size_t)(TT + 1) * SLOT * 2, 0, SLOT * 2, stream); // dir1

  hipLaunchKernelGGL(xprep_kernel, dim3(4096), dim3(256), 0, stream, input, xbf);
  hipLaunchKernelGGL(lstm_kernel, dim3(512), dim3(256), 0, stream,
                     Wih_f, Whh_f, bih_f, bhh_f, Wih_b, Whh_b, bih_b, bhh_b,
                     xbf, h_hist, flags, claim, (float*)d_out);
}